// Round 11
// baseline (396.398 us; speedup 1.0000x reference)
//
#include <hip/hip_runtime.h>

typedef __attribute__((ext_vector_type(8))) short bf16x8;
typedef __attribute__((ext_vector_type(4))) float f32x4;
typedef __attribute__((ext_vector_type(16))) float f32x16;

__device__ __forceinline__ unsigned short f2bf(float f) {  // RNE
    union { float f; unsigned u; } v; v.f = f;
    return (unsigned short)((v.u + 0x7FFFu + ((v.u >> 16) & 1u)) >> 16);
}

__device__ __forceinline__ float fexp2(float v) {
#if __has_builtin(__builtin_amdgcn_exp2f)
    return __builtin_amdgcn_exp2f(v);
#else
    float r; asm("v_exp_f32 %0, %1" : "=v"(r) : "v"(v)); return r;
#endif
}
// pack two f32 -> two bf16 (RNE) in one instr (T12 primitive)
__device__ __forceinline__ unsigned cvt_pk_bf16(float lo, float hi) {
    unsigned r;
    asm("v_cvt_pk_bf16_f32 %0, %1, %2" : "=v"(r) : "v"(lo), "v"(hi));
    return r;
}

__device__ __forceinline__ void async16(unsigned short* lds, const unsigned short* gsrc) {
    __builtin_amdgcn_global_load_lds(
        (const __attribute__((address_space(1))) void*)gsrc,
        (__attribute__((address_space(3))) void*)lds, 16, 0, 0);
}

// ---------------- Kernel 0: weight transpose + bf16 cast (swizzled) ------
// kf rows (n<32) pre-scaled by log2(e): softmax exp(s) == exp2(s_scaled).
__global__ __launch_bounds__(256) void k_wt(const float* __restrict__ kf,
                                            const float* __restrict__ kg,
                                            const float* __restrict__ kh,
                                            unsigned short* __restrict__ wt) {
    int n = blockIdx.x, t = threadIdx.x;
    const float* src; int stride, col;
    if (n < 32)      { src = kf; stride = 32;  col = n; }
    else if (n < 64) { src = kg; stride = 32;  col = n - 32; }
    else             { src = kh; stride = 256; col = n - 64; }
    float v = src[t * stride + col];
    if (n < 32) v *= 1.44269504088896341f;     // log2(e)
    wt[n * 256 + (((t >> 3) ^ (n & 7)) << 3) + (t & 7)] = f2bf(v);
}

// ---------------- Kernel 1: projections (R8 verified, unchanged) ---------
// hT2[b][kb][ch][k8]: kb = key>>3, k8 = key&7 -> k_attn PV fragments are
// coalesced 16B-per-lane global loads.
__global__ __launch_bounds__(512) void k_proj(const float* __restrict__ x,
                                              const unsigned short* __restrict__ wt,
                                              unsigned short* __restrict__ f,
                                              unsigned short* __restrict__ g,
                                              unsigned short* __restrict__ hT) {
    __shared__ unsigned short xs[8192];       // 32 x 256 bf16, swizzled  16 KB
    __shared__ unsigned short ws[16384];      // one 64-col W tile        32 KB
    int t = threadIdx.x, rb = blockIdx.x;     // 512 row-blocks of 32 rows
    int w = t >> 6, lane = t & 63, q = lane >> 4, n15 = lane & 15;
    int b = rb >> 7, nbase = (rb & 127) * 32;
    int rg0 = w & 1, cg0 = w >> 1;            // ct0: 2 rowg x 4 colg
    int cgh = w & 3, rgh = w >> 2;            // ct>=1: 4 chg x 2 rowg

#pragma unroll
    for (int i = 0; i < 4; ++i) {
        int lin = i * 512 + t, row = lin >> 6, c4 = lin & 63;
        float4 v = *(const float4*)&x[(rb * 32 + row) * 256 + c4 * 4];
        ushort4 o; o.x = f2bf(v.x); o.y = f2bf(v.y); o.z = f2bf(v.z); o.w = f2bf(v.w);
        *(ushort4*)&xs[row * 256 + (((c4 >> 1) ^ (row & 7)) << 3) + ((c4 & 1) << 2)] = o;
    }
#pragma unroll
    for (int j = 0; j < 4; ++j)
        async16(&ws[(j * 512 + w * 64) * 8], wt + (j * 512 + t) * 8);
    __syncthreads();                           // xs + tile0 ready

    for (int ct = 0; ct < 5; ++ct) {
        f32x4 acc = (f32x4){0.f, 0.f, 0.f, 0.f};
        if (ct == 0) {                         // f,g : D[m=row][n=col]
#pragma unroll
            for (int kk = 0; kk < 8; ++kk) {
                bf16x8 a = *(const bf16x8*)&xs[(rg0 * 16 + n15) * 256
                                + ((((kk << 2) + q) ^ (n15 & 7)) << 3)];
                bf16x8 bw = *(const bf16x8*)&ws[(cg0 * 16 + n15) * 256
                                + ((((kk << 2) + q) ^ (n15 & 7)) << 3)];
                acc = __builtin_amdgcn_mfma_f32_16x16x32_bf16(a, bw, acc, 0, 0, 0);
            }
        } else {                               // h : D[m=ch][n=row] (swapped)
#pragma unroll
            for (int kk = 0; kk < 8; ++kk) {
                bf16x8 a = *(const bf16x8*)&ws[(cgh * 16 + n15) * 256
                                + ((((kk << 2) + q) ^ (n15 & 7)) << 3)];
                bf16x8 bx = *(const bf16x8*)&xs[(rgh * 16 + n15) * 256
                                + ((((kk << 2) + q) ^ (n15 & 7)) << 3)];
                acc = __builtin_amdgcn_mfma_f32_16x16x32_bf16(a, bx, acc, 0, 0, 0);
            }
        }
        __syncthreads();                       // all waves done reading ws
        if (ct < 4) {                          // DMA tile ct+1 (flies over stores)
            const unsigned short* wsrc = wt + (ct + 1) * 16384;
#pragma unroll
            for (int j = 0; j < 4; ++j)
                async16(&ws[(j * 512 + w * 64) * 8], wsrc + (j * 512 + t) * 8);
        }
        if (ct == 0) {                         // store f/g (overlaps DMA)
#pragma unroll
            for (int r = 0; r < 4; ++r) {
                int grow = rb * 32 + rg0 * 16 + q * 4 + r;
                int col = cg0 * 16 + n15;
                unsigned short v = f2bf(acc[r]);
                if (col < 32) f[grow * 32 + col] = v;
                else          g[grow * 32 + (col - 32)] = v;
            }
        } else {                               // store hT2 (overlaps DMA)
#pragma unroll
            for (int r = 0; r < 4; ++r) {
                int ch = (ct - 1) * 64 + cgh * 16 + q * 4 + r;
                int key = nbase + rgh * 16 + n15;
                hT[((b * 512 + (key >> 3)) * 256 + ch) * 8 + (key & 7)] = f2bf(acc[r]);
            }
        }
        __syncthreads();                       // tile ct+1 landed
    }
}

// ---------------- Kernel 2: fused flash attention + residual -------------
// R8 structure (56.7 us verified) with ONE change: Q-tile 64 -> 32 rows,
// grid 512 -> 1024 = 4 WGs/CU (was 2). Diagnosis: wall 2126 cy/iter/SIMD
// vs busiest pipe ~820 cy -> latency/barrier-bound with starved TLP.
// Same total chip work (exp count, MFMA count, pls bytes identical; only
// L2-hot g/H re-reads double). Per-WG state shrinks: aFB[2], one o0
// accumulator, pls 32 rows (9.3 KB LDS) -> 8 waves/SIMD at VGPR<=64
// (__launch_bounds__(512,8); R8 path fit in 56).
__global__ __launch_bounds__(512, 8) void k_attn(const float* __restrict__ x,
                                                 const unsigned short* __restrict__ f,
                                                 const unsigned short* __restrict__ g,
                                                 const unsigned short* __restrict__ hT,
                                                 const float* __restrict__ gamma_p,
                                                 float* __restrict__ out) {
    __shared__ unsigned short pls[2][2048];    // P dbuf: 32 rows x 64 keys  8 KB
    __shared__ float lpart[4][32];             // per-S-wave key-partial row sums
    __shared__ __align__(16) float lrec[32];   // per-row 1/l
    int t = threadIdx.x, bx = blockIdx.x;
    int b = (bx >> 1) & 3;                     // one batch per XCD-pair
    int ch2 = (bx >> 3) & 1;                   // channel half (128 ch)
    int qt = ((bx & 1) << 6) | (bx >> 4);      // 128 Q-tiles of 32 rows
    int qbase = qt * 32;
    int chbase = ch2 * 128;
    int w = t >> 6, l = t & 63;
    int hi = l >> 5, l31 = l & 31;             // 32x32 roles (PV)
    int q = l >> 4, n15 = l & 15;              // 16x16 roles (S)
    int cb = w & 3;                            // PV ch-block (w>=4)
    const bool is_s = (w < 4);

    // ---- S-wave state: key-split. Wave w owns keys [kt*64+w*16, +16). ----
    bf16x8 aFB[2];
    const unsigned short* gW = g + (b * 4096 + w * 16 + n15) * 32 + q * 8;  // +kt*2048
    if (is_s) {
#pragma unroll
        for (int nt = 0; nt < 2; ++nt)
            aFB[nt] = *(const bf16x8*)&f[(b * 4096 + qbase + nt * 16 + n15) * 32 + q * 8];
    }
    bf16x8 aG, aGn;
    float lac0 = 0.f, lac1 = 0.f;              // l partials per nt (row group)
    const f32x4 zero4 = (f32x4){0.f, 0.f, 0.f, 0.f};

    // ---- PV-wave state: coalesced hT2 pointer + reg dbuf ----
    // hT2 idx = ((b*512 + kb)*256 + ch)*8 + k8 ; kb = kt*8 + 2ks + hi.
    const unsigned short* hb2 = hT + b * 1048576
                              + (chbase + cb * 32 + l31) * 8 + hi * 2048;
    bf16x8 bHc[4], bHn[4];

    // S-step for tile in aG -> pls[buf].
    // D[m=key w*16+4q+r][n=qrow nt*16+n15]; key-quad kq = 4w+q.
    auto s_tile = [&](int buf) {
        f32x4 sa[2];
#pragma unroll
        for (int nt = 0; nt < 2; ++nt)
            sa[nt] = __builtin_amdgcn_mfma_f32_16x16x32_bf16(aG, aFB[nt], zero4, 0, 0, 0);
        int kq = w * 4 + q;
#pragma unroll
        for (int nt = 0; nt < 2; ++nt) {
#pragma unroll
            for (int r = 0; r < 4; ++r) {
                sa[nt][r] = fexp2(sa[nt][r]);  // f pre-scaled by log2(e)
                if (nt == 0) lac0 += sa[nt][r]; else lac1 += sa[nt][r];
            }
            unsigned p0 = cvt_pk_bf16(sa[nt][0], sa[nt][1]);
            unsigned p1 = cvt_pk_bf16(sa[nt][2], sa[nt][3]);
            int row = nt * 16 + n15;
            // phys = row*128B + ((kq>>1)^(row&7))*16B + (kq&1)*8B
            unsigned* dst = (unsigned*)&pls[buf][row * 64]
                          + (((kq >> 1) ^ (n15 & 7)) << 2) + ((kq & 1) << 1);
            dst[0] = p0; dst[1] = p1;
        }
    };

    f32x16 o0;
#pragma unroll
    for (int i = 0; i < 16; ++i) o0[i] = 0.f;

    // ---- prologue: S(0) -> pls[0]; PV loads bH(0); aG <- tile 1 ----
    if (is_s) {
        aG  = *(const bf16x8*)&gW[0];
        aGn = *(const bf16x8*)&gW[2048];
        s_tile(0);
        aG = aGn;
        __builtin_amdgcn_sched_barrier(0);
        asm volatile("s_waitcnt lgkmcnt(0)" ::: "memory");
    } else {
#pragma unroll
        for (int ks = 0; ks < 4; ++ks)
            bHc[ks] = *(const bf16x8*)&hb2[ks * 4096];
        __builtin_amdgcn_sched_barrier(0);
    }
    __builtin_amdgcn_s_barrier();              // publishes pls[0]
    __builtin_amdgcn_sched_barrier(0);

#pragma unroll 2
    for (int kt = 0; kt < 64; ++kt) {
        int cur = kt & 1, nxt = cur ^ 1;

        if (is_s) {
            if (kt + 1 < 64) {
                int ktn = (kt + 2 < 64) ? kt + 2 : 63;
                aGn = *(const bf16x8*)&gW[ktn * 2048];   // flies during s_tile
                s_tile(nxt);                             // S(kt+1) from aG
                aG = aGn;
            }
            __builtin_amdgcn_sched_barrier(0);
            asm volatile("s_waitcnt lgkmcnt(0)" ::: "memory");  // pls[nxt] visible
        } else {
            if (kt + 1 < 64) {                 // issue bH(kt+1) early (T14)
#pragma unroll
                for (int ks = 0; ks < 4; ++ks)
                    bHn[ks] = *(const bf16x8*)&hb2[(kt + 1) * 16384 + ks * 4096];
            }
            // ---- O += P(kt).H(kt) : 32x32x16, 4 key-steps ----
            const unsigned short* pcur = &pls[cur][0];
            __builtin_amdgcn_s_setprio(1);
#pragma unroll
            for (int ks = 0; ks < 4; ++ks) {
                int seg = (((2 * ks + hi) ^ (l31 & 7)) << 3);
                bf16x8 aP0 = *(const bf16x8*)&pcur[l31 * 64 + seg];
                o0 = __builtin_amdgcn_mfma_f32_32x32x16_bf16(aP0, bHc[ks], o0, 0, 0, 0);
            }
            __builtin_amdgcn_s_setprio(0);
            if (kt + 1 < 64) {
#pragma unroll
                for (int ks = 0; ks < 4; ++ks) bHc[ks] = bHn[ks];
            }
            __builtin_amdgcn_sched_barrier(0);
        }

        __builtin_amdgcn_s_barrier();          // publish pls[nxt]
        __builtin_amdgcn_sched_barrier(0);
    }

    // ---- epilogue: l reduce (4 key-partials per row), O/l, residual ----
    if (is_s) {
        float ps0 = lac0, ps1 = lac1;
        ps0 += __shfl_xor(ps0, 16); ps0 += __shfl_xor(ps0, 32);
        ps1 += __shfl_xor(ps1, 16); ps1 += __shfl_xor(ps1, 32);
        if (q == 0) { lpart[w][n15] = ps0; lpart[w][16 + n15] = ps1; }
    }
    __syncthreads();
    if (t < 32) lrec[t] = 1.0f / (lpart[0][t] + lpart[1][t] + lpart[2][t] + lpart[3][t]);
    __syncthreads();
    if (!is_s) {
        float gam = *gamma_p;
        int ch = chbase + cb * 32 + l31;
#pragma unroll
        for (int qq = 0; qq < 4; ++qq) {
            int r0 = 8 * qq + 4 * hi;
            f32x4 ri0 = *(const f32x4*)&lrec[r0];
#pragma unroll
            for (int j = 0; j < 4; ++j) {
                int idx0 = (b * 4096 + qbase + r0 + j) * 256 + ch;
                out[idx0] = x[idx0] + gam * (o0[4 * qq + j] * ri0[j]);
            }
        }
    }
}

// ---------------- launch ------------------------------------------------
extern "C" void kernel_launch(void* const* d_in, const int* in_sizes, int n_in,
                              void* d_out, int out_size, void* d_ws, size_t ws_size,
                              hipStream_t stream) {
    const float* x  = (const float*)d_in[0];
    const float* kf = (const float*)d_in[1];
    const float* kg = (const float*)d_in[2];
    const float* kh = (const float*)d_in[3];
    const float* gm = (const float*)d_in[4];
    float* out = (float*)d_out;

    char* ws = (char*)d_ws;
    unsigned short* wt = (unsigned short*)(ws);             // 320*256*2   = 163840 B
    unsigned short* fb = (unsigned short*)(ws + 163840);    // 16384*32*2  = 1 MiB
    unsigned short* gb = (unsigned short*)(ws + 1212416);   // 16384*32*2  = 1 MiB
    unsigned short* hT = (unsigned short*)(ws + 2260992);   // 4*512*256*8*2 = 8 MiB

    hipLaunchKernelGGL(k_wt,   dim3(320), dim3(256), 0, stream, kf, kg, kh, wt);
    hipLaunchKernelGGL(k_proj, dim3(512), dim3(512), 0, stream, x, wt, fb, gb, hT);
    hipLaunchKernelGGL(k_attn, dim3(1024), dim3(512), 0, stream, x, fb, gb, hT, gm, out);
}

// Round 12
// 149.817 us; speedup vs baseline: 2.6459x; 2.6459x over previous
//
#include <hip/hip_runtime.h>

typedef __attribute__((ext_vector_type(8))) short bf16x8;
typedef __attribute__((ext_vector_type(4))) float f32x4;
typedef __attribute__((ext_vector_type(16))) float f32x16;

__device__ __forceinline__ unsigned short f2bf(float f) {  // RNE
    union { float f; unsigned u; } v; v.f = f;
    return (unsigned short)((v.u + 0x7FFFu + ((v.u >> 16) & 1u)) >> 16);
}

__device__ __forceinline__ float fexp2(float v) {
#if __has_builtin(__builtin_amdgcn_exp2f)
    return __builtin_amdgcn_exp2f(v);
#else
    float r; asm("v_exp_f32 %0, %1" : "=v"(r) : "v"(v)); return r;
#endif
}
// pack two f32 -> two bf16 (RNE) in one instr (T12 primitive)
__device__ __forceinline__ unsigned cvt_pk_bf16(float lo, float hi) {
    unsigned r;
    asm("v_cvt_pk_bf16_f32 %0, %1, %2" : "=v"(r) : "v"(lo), "v"(hi));
    return r;
}

__device__ __forceinline__ void async16(unsigned short* lds, const unsigned short* gsrc) {
    __builtin_amdgcn_global_load_lds(
        (const __attribute__((address_space(1))) void*)gsrc,
        (__attribute__((address_space(3))) void*)lds, 16, 0, 0);
}

// ---------------- Kernel 0: weight transpose + bf16 cast (swizzled) ------
// kf rows (n<32) pre-scaled by log2(e): softmax exp(s) == exp2(s_scaled).
__global__ __launch_bounds__(256) void k_wt(const float* __restrict__ kf,
                                            const float* __restrict__ kg,
                                            const float* __restrict__ kh,
                                            unsigned short* __restrict__ wt) {
    int n = blockIdx.x, t = threadIdx.x;
    const float* src; int stride, col;
    if (n < 32)      { src = kf; stride = 32;  col = n; }
    else if (n < 64) { src = kg; stride = 32;  col = n - 32; }
    else             { src = kh; stride = 256; col = n - 64; }
    float v = src[t * stride + col];
    if (n < 32) v *= 1.44269504088896341f;     // log2(e)
    wt[n * 256 + (((t >> 3) ^ (n & 7)) << 3) + (t & 7)] = f2bf(v);
}

// ---------------- Kernel 1: projections (R8 verified, unchanged) ---------
// hT2[b][kb][ch][k8]: kb = key>>3, k8 = key&7 -> k_attn PV fragments are
// coalesced 16B-per-lane global loads.
__global__ __launch_bounds__(512) void k_proj(const float* __restrict__ x,
                                              const unsigned short* __restrict__ wt,
                                              unsigned short* __restrict__ f,
                                              unsigned short* __restrict__ g,
                                              unsigned short* __restrict__ hT) {
    __shared__ unsigned short xs[8192];       // 32 x 256 bf16, swizzled  16 KB
    __shared__ unsigned short ws[16384];      // one 64-col W tile        32 KB
    int t = threadIdx.x, rb = blockIdx.x;     // 512 row-blocks of 32 rows
    int w = t >> 6, lane = t & 63, q = lane >> 4, n15 = lane & 15;
    int b = rb >> 7, nbase = (rb & 127) * 32;
    int rg0 = w & 1, cg0 = w >> 1;            // ct0: 2 rowg x 4 colg
    int cgh = w & 3, rgh = w >> 2;            // ct>=1: 4 chg x 2 rowg

#pragma unroll
    for (int i = 0; i < 4; ++i) {
        int lin = i * 512 + t, row = lin >> 6, c4 = lin & 63;
        float4 v = *(const float4*)&x[(rb * 32 + row) * 256 + c4 * 4];
        ushort4 o; o.x = f2bf(v.x); o.y = f2bf(v.y); o.z = f2bf(v.z); o.w = f2bf(v.w);
        *(ushort4*)&xs[row * 256 + (((c4 >> 1) ^ (row & 7)) << 3) + ((c4 & 1) << 2)] = o;
    }
#pragma unroll
    for (int j = 0; j < 4; ++j)
        async16(&ws[(j * 512 + w * 64) * 8], wt + (j * 512 + t) * 8);
    __syncthreads();                           // xs + tile0 ready

    for (int ct = 0; ct < 5; ++ct) {
        f32x4 acc = (f32x4){0.f, 0.f, 0.f, 0.f};
        if (ct == 0) {                         // f,g : D[m=row][n=col]
#pragma unroll
            for (int kk = 0; kk < 8; ++kk) {
                bf16x8 a = *(const bf16x8*)&xs[(rg0 * 16 + n15) * 256
                                + ((((kk << 2) + q) ^ (n15 & 7)) << 3)];
                bf16x8 bw = *(const bf16x8*)&ws[(cg0 * 16 + n15) * 256
                                + ((((kk << 2) + q) ^ (n15 & 7)) << 3)];
                acc = __builtin_amdgcn_mfma_f32_16x16x32_bf16(a, bw, acc, 0, 0, 0);
            }
        } else {                               // h : D[m=ch][n=row] (swapped)
#pragma unroll
            for (int kk = 0; kk < 8; ++kk) {
                bf16x8 a = *(const bf16x8*)&ws[(cgh * 16 + n15) * 256
                                + ((((kk << 2) + q) ^ (n15 & 7)) << 3)];
                bf16x8 bx = *(const bf16x8*)&xs[(rgh * 16 + n15) * 256
                                + ((((kk << 2) + q) ^ (n15 & 7)) << 3)];
                acc = __builtin_amdgcn_mfma_f32_16x16x32_bf16(a, bx, acc, 0, 0, 0);
            }
        }
        __syncthreads();                       // all waves done reading ws
        if (ct < 4) {                          // DMA tile ct+1 (flies over stores)
            const unsigned short* wsrc = wt + (ct + 1) * 16384;
#pragma unroll
            for (int j = 0; j < 4; ++j)
                async16(&ws[(j * 512 + w * 64) * 8], wsrc + (j * 512 + t) * 8);
        }
        if (ct == 0) {                         // store f/g (overlaps DMA)
#pragma unroll
            for (int r = 0; r < 4; ++r) {
                int grow = rb * 32 + rg0 * 16 + q * 4 + r;
                int col = cg0 * 16 + n15;
                unsigned short v = f2bf(acc[r]);
                if (col < 32) f[grow * 32 + col] = v;
                else          g[grow * 32 + (col - 32)] = v;
            }
        } else {                               // store hT2 (overlaps DMA)
#pragma unroll
            for (int r = 0; r < 4; ++r) {
                int ch = (ct - 1) * 64 + cgh * 16 + q * 4 + r;
                int key = nbase + rgh * 16 + n15;
                hT[((b * 512 + (key >> 3)) * 256 + ch) * 8 + (key & 7)] = f2bf(acc[r]);
            }
        }
        __syncthreads();                       // tile ct+1 landed
    }
}

// ---------------- Kernel 2: fused flash attention + residual -------------
// R10 structure (Q-tile 32 rows, grid 1024 = up to 4 WGs/CU) with the
// launch bound FIXED: R11's __launch_bounds__(512,8) forced a 32-VGPR
// allocation -> ~50-reg working set spilled to scratch (WRITE 616 MB,
// 332us). Now (512,4): 128-VGPR cap, natural usage ~50-60 (R8's larger
// body compiled to 52-56 under the same bound). HW occupancy follows
// ACTUAL usage: <=64 VGPR -> 8 waves/SIMD -> 4 WGs/CU resident.
__global__ __launch_bounds__(512, 4) void k_attn(const float* __restrict__ x,
                                                 const unsigned short* __restrict__ f,
                                                 const unsigned short* __restrict__ g,
                                                 const unsigned short* __restrict__ hT,
                                                 const float* __restrict__ gamma_p,
                                                 float* __restrict__ out) {
    __shared__ unsigned short pls[2][2048];    // P dbuf: 32 rows x 64 keys  8 KB
    __shared__ float lpart[4][32];             // per-S-wave key-partial row sums
    __shared__ __align__(16) float lrec[32];   // per-row 1/l
    int t = threadIdx.x, bx = blockIdx.x;
    int b = (bx >> 1) & 3;                     // one batch per XCD-pair
    int ch2 = (bx >> 3) & 1;                   // channel half (128 ch)
    int qt = ((bx & 1) << 6) | (bx >> 4);      // 128 Q-tiles of 32 rows
    int qbase = qt * 32;
    int chbase = ch2 * 128;
    int w = t >> 6, l = t & 63;
    int hi = l >> 5, l31 = l & 31;             // 32x32 roles (PV)
    int q = l >> 4, n15 = l & 15;              // 16x16 roles (S)
    int cb = w & 3;                            // PV ch-block (w>=4)
    const bool is_s = (w < 4);

    // ---- S-wave state: key-split. Wave w owns keys [kt*64+w*16, +16). ----
    bf16x8 aFB[2];
    const unsigned short* gW = g + (b * 4096 + w * 16 + n15) * 32 + q * 8;  // +kt*2048
    if (is_s) {
#pragma unroll
        for (int nt = 0; nt < 2; ++nt)
            aFB[nt] = *(const bf16x8*)&f[(b * 4096 + qbase + nt * 16 + n15) * 32 + q * 8];
    }
    bf16x8 aG, aGn;
    float lac0 = 0.f, lac1 = 0.f;              // l partials per nt (row group)
    const f32x4 zero4 = (f32x4){0.f, 0.f, 0.f, 0.f};

    // ---- PV-wave state: coalesced hT2 pointer + reg dbuf ----
    // hT2 idx = ((b*512 + kb)*256 + ch)*8 + k8 ; kb = kt*8 + 2ks + hi.
    const unsigned short* hb2 = hT + b * 1048576
                              + (chbase + cb * 32 + l31) * 8 + hi * 2048;
    bf16x8 bHc[4], bHn[4];

    // S-step for tile in aG -> pls[buf].
    // D[m=key w*16+4q+r][n=qrow nt*16+n15]; key-quad kq = 4w+q.
    auto s_tile = [&](int buf) {
        f32x4 sa[2];
#pragma unroll
        for (int nt = 0; nt < 2; ++nt)
            sa[nt] = __builtin_amdgcn_mfma_f32_16x16x32_bf16(aG, aFB[nt], zero4, 0, 0, 0);
        int kq = w * 4 + q;
#pragma unroll
        for (int nt = 0; nt < 2; ++nt) {
#pragma unroll
            for (int r = 0; r < 4; ++r) {
                sa[nt][r] = fexp2(sa[nt][r]);  // f pre-scaled by log2(e)
                if (nt == 0) lac0 += sa[nt][r]; else lac1 += sa[nt][r];
            }
            unsigned p0 = cvt_pk_bf16(sa[nt][0], sa[nt][1]);
            unsigned p1 = cvt_pk_bf16(sa[nt][2], sa[nt][3]);
            int row = nt * 16 + n15;
            // phys = row*128B + ((kq>>1)^(row&7))*16B + (kq&1)*8B
            unsigned* dst = (unsigned*)&pls[buf][row * 64]
                          + (((kq >> 1) ^ (n15 & 7)) << 2) + ((kq & 1) << 1);
            dst[0] = p0; dst[1] = p1;
        }
    };

    f32x16 o0;
#pragma unroll
    for (int i = 0; i < 16; ++i) o0[i] = 0.f;

    // ---- prologue: S(0) -> pls[0]; PV loads bH(0); aG <- tile 1 ----
    if (is_s) {
        aG  = *(const bf16x8*)&gW[0];
        aGn = *(const bf16x8*)&gW[2048];
        s_tile(0);
        aG = aGn;
        __builtin_amdgcn_sched_barrier(0);
        asm volatile("s_waitcnt lgkmcnt(0)" ::: "memory");
    } else {
#pragma unroll
        for (int ks = 0; ks < 4; ++ks)
            bHc[ks] = *(const bf16x8*)&hb2[ks * 4096];
        __builtin_amdgcn_sched_barrier(0);
    }
    __builtin_amdgcn_s_barrier();              // publishes pls[0]
    __builtin_amdgcn_sched_barrier(0);

#pragma unroll 2
    for (int kt = 0; kt < 64; ++kt) {
        int cur = kt & 1, nxt = cur ^ 1;

        if (is_s) {
            if (kt + 1 < 64) {
                int ktn = (kt + 2 < 64) ? kt + 2 : 63;
                aGn = *(const bf16x8*)&gW[ktn * 2048];   // flies during s_tile
                s_tile(nxt);                             // S(kt+1) from aG
                aG = aGn;
            }
            __builtin_amdgcn_sched_barrier(0);
            asm volatile("s_waitcnt lgkmcnt(0)" ::: "memory");  // pls[nxt] visible
        } else {
            if (kt + 1 < 64) {                 // issue bH(kt+1) early (T14)
#pragma unroll
                for (int ks = 0; ks < 4; ++ks)
                    bHn[ks] = *(const bf16x8*)&hb2[(kt + 1) * 16384 + ks * 4096];
            }
            // ---- O += P(kt).H(kt) : 32x32x16, 4 key-steps ----
            const unsigned short* pcur = &pls[cur][0];
            __builtin_amdgcn_s_setprio(1);
#pragma unroll
            for (int ks = 0; ks < 4; ++ks) {
                int seg = (((2 * ks + hi) ^ (l31 & 7)) << 3);
                bf16x8 aP0 = *(const bf16x8*)&pcur[l31 * 64 + seg];
                o0 = __builtin_amdgcn_mfma_f32_32x32x16_bf16(aP0, bHc[ks], o0, 0, 0, 0);
            }
            __builtin_amdgcn_s_setprio(0);
            if (kt + 1 < 64) {
#pragma unroll
                for (int ks = 0; ks < 4; ++ks) bHc[ks] = bHn[ks];
            }
            __builtin_amdgcn_sched_barrier(0);
        }

        __builtin_amdgcn_s_barrier();          // publish pls[nxt]
        __builtin_amdgcn_sched_barrier(0);
    }

    // ---- epilogue: l reduce (4 key-partials per row), O/l, residual ----
    if (is_s) {
        float ps0 = lac0, ps1 = lac1;
        ps0 += __shfl_xor(ps0, 16); ps0 += __shfl_xor(ps0, 32);
        ps1 += __shfl_xor(ps1, 16); ps1 += __shfl_xor(ps1, 32);
        if (q == 0) { lpart[w][n15] = ps0; lpart[w][16 + n15] = ps1; }
    }
    __syncthreads();
    if (t < 32) lrec[t] = 1.0f / (lpart[0][t] + lpart[1][t] + lpart[2][t] + lpart[3][t]);
    __syncthreads();
    if (!is_s) {
        float gam = *gamma_p;
        int ch = chbase + cb * 32 + l31;
#pragma unroll
        for (int qq = 0; qq < 4; ++qq) {
            int r0 = 8 * qq + 4 * hi;
            f32x4 ri0 = *(const f32x4*)&lrec[r0];
#pragma unroll
            for (int j = 0; j < 4; ++j) {
                int idx0 = (b * 4096 + qbase + r0 + j) * 256 + ch;
                out[idx0] = x[idx0] + gam * (o0[4 * qq + j] * ri0[j]);
            }
        }
    }
}

// ---------------- launch ------------------------------------------------
extern "C" void kernel_launch(void* const* d_in, const int* in_sizes, int n_in,
                              void* d_out, int out_size, void* d_ws, size_t ws_size,
                              hipStream_t stream) {
    const float* x  = (const float*)d_in[0];
    const float* kf = (const float*)d_in[1];
    const float* kg = (const float*)d_in[2];
    const float* kh = (const float*)d_in[3];
    const float* gm = (const float*)d_in[4];
    float* out = (float*)d_out;

    char* ws = (char*)d_ws;
    unsigned short* wt = (unsigned short*)(ws);             // 320*256*2   = 163840 B
    unsigned short* fb = (unsigned short*)(ws + 163840);    // 16384*32*2  = 1 MiB
    unsigned short* gb = (unsigned short*)(ws + 1212416);   // 16384*32*2  = 1 MiB
    unsigned short* hT = (unsigned short*)(ws + 2260992);   // 4*512*256*8*2 = 8 MiB

    hipLaunchKernelGGL(k_wt,   dim3(320), dim3(256), 0, stream, kf, kg, kh, wt);
    hipLaunchKernelGGL(k_proj, dim3(512), dim3(512), 0, stream, x, wt, fb, gb, hT);
    hipLaunchKernelGGL(k_attn, dim3(1024), dim3(512), 0, stream, x, fb, gb, hT, gm, out);
}

// Round 13
// 149.604 us; speedup vs baseline: 2.6496x; 1.0014x over previous
//
#include <hip/hip_runtime.h>

typedef __attribute__((ext_vector_type(8))) short bf16x8;
typedef __attribute__((ext_vector_type(4))) float f32x4;
typedef __attribute__((ext_vector_type(16))) float f32x16;

__device__ __forceinline__ unsigned short f2bf(float f) {  // RNE
    union { float f; unsigned u; } v; v.f = f;
    return (unsigned short)((v.u + 0x7FFFu + ((v.u >> 16) & 1u)) >> 16);
}

__device__ __forceinline__ float fexp2(float v) {
#if __has_builtin(__builtin_amdgcn_exp2f)
    return __builtin_amdgcn_exp2f(v);
#else
    float r; asm("v_exp_f32 %0, %1" : "=v"(r) : "v"(v)); return r;
#endif
}
// pack two f32 -> two bf16 (RNE) in one instr (T12 primitive)
__device__ __forceinline__ unsigned cvt_pk_bf16(float lo, float hi) {
    unsigned r;
    asm("v_cvt_pk_bf16_f32 %0, %1, %2" : "=v"(r) : "v"(lo), "v"(hi));
    return r;
}

// ---------------- Kernel 1: projections + inline weight transpose --------
// R8-verified body; the k_wt dispatch is gone. Each WG transposes its own
// weight tile from global fp32 into ws (bf16, swizzled — same layout the
// verified fragment reads expect). Reads are coalesced float4 along the
// output-channel axis (128-256B runs, L2-resident 320 KB); kf pre-scaled
// by log2(e) so k_attn's softmax uses raw v_exp_f32 (exp2).
// Tile map (wt col n): ct0 = kf(0-31)+kg(0-31); ct>=1 = kh cols (ct-1)*64..
// hT2[b][kb][ch][k8]: kb = key>>3, k8 = key&7 -> k_attn PV fragments are
// coalesced 16B-per-lane global loads.
__global__ __launch_bounds__(512) void k_proj(const float* __restrict__ x,
                                              const float* __restrict__ kf,
                                              const float* __restrict__ kg,
                                              const float* __restrict__ kh,
                                              unsigned short* __restrict__ f,
                                              unsigned short* __restrict__ g,
                                              unsigned short* __restrict__ hT) {
    __shared__ unsigned short xs[8192];       // 32 x 256 bf16, swizzled  16 KB
    __shared__ unsigned short ws[16384];      // one 64-col W tile        32 KB
    int t = threadIdx.x, rb = blockIdx.x;     // 512 row-blocks of 32 rows
    int w = t >> 6, lane = t & 63, q = lane >> 4, n15 = lane & 15;
    int b = rb >> 7, nbase = (rb & 127) * 32;
    int rg0 = w & 1, cg0 = w >> 1;            // ct0: 2 rowg x 4 colg
    int cgh = w & 3, rgh = w >> 2;            // ct>=1: 4 chg x 2 rowg

    // inline transpose of tile ct into ws (64 cols x 256 k)
    auto stage_w = [&](int ct) {
#pragma unroll
        for (int i = 0; i < 8; ++i) {
            int lin = i * 512 + t;
            int k = lin >> 4, q4 = lin & 15;   // 16 float4-quads per k-row
            float4 v; int nl; float scale = 1.0f;
            if (ct == 0) {
                if (q4 < 8) { v = *(const float4*)&kf[k * 32 + q4 * 4];
                              nl = q4 * 4; scale = 1.44269504088896341f; }
                else        { v = *(const float4*)&kg[k * 32 + (q4 - 8) * 4];
                              nl = 32 + (q4 - 8) * 4; }
            } else {
                v = *(const float4*)&kh[k * 256 + (ct - 1) * 64 + q4 * 4];
                nl = q4 * 4;
            }
            int kseg = (k >> 3), k7 = k & 7;
            float vv[4] = {v.x, v.y, v.z, v.w};
#pragma unroll
            for (int j = 0; j < 4; ++j) {
                int n = nl + j;
                ws[n * 256 + ((kseg ^ (n & 7)) << 3) + k7] = f2bf(vv[j] * scale);
            }
        }
    };

    // stage xs: 32 rows x 256 fp32 -> bf16 (4 float4/thread)
#pragma unroll
    for (int i = 0; i < 4; ++i) {
        int lin = i * 512 + t, row = lin >> 6, c4 = lin & 63;
        float4 v = *(const float4*)&x[(rb * 32 + row) * 256 + c4 * 4];
        ushort4 o; o.x = f2bf(v.x); o.y = f2bf(v.y); o.z = f2bf(v.z); o.w = f2bf(v.w);
        *(ushort4*)&xs[row * 256 + (((c4 >> 1) ^ (row & 7)) << 3) + ((c4 & 1) << 2)] = o;
    }
    stage_w(0);
    __syncthreads();                           // xs + tile0 ready

    for (int ct = 0; ct < 5; ++ct) {
        f32x4 acc = (f32x4){0.f, 0.f, 0.f, 0.f};
        if (ct == 0) {                         // f,g : D[m=row][n=col]
#pragma unroll
            for (int kk = 0; kk < 8; ++kk) {
                bf16x8 a = *(const bf16x8*)&xs[(rg0 * 16 + n15) * 256
                                + ((((kk << 2) + q) ^ (n15 & 7)) << 3)];
                bf16x8 bw = *(const bf16x8*)&ws[(cg0 * 16 + n15) * 256
                                + ((((kk << 2) + q) ^ (n15 & 7)) << 3)];
                acc = __builtin_amdgcn_mfma_f32_16x16x32_bf16(a, bw, acc, 0, 0, 0);
            }
        } else {                               // h : D[m=ch][n=row] (swapped)
#pragma unroll
            for (int kk = 0; kk < 8; ++kk) {
                bf16x8 a = *(const bf16x8*)&ws[(cgh * 16 + n15) * 256
                                + ((((kk << 2) + q) ^ (n15 & 7)) << 3)];
                bf16x8 bx = *(const bf16x8*)&xs[(rgh * 16 + n15) * 256
                                + ((((kk << 2) + q) ^ (n15 & 7)) << 3)];
                acc = __builtin_amdgcn_mfma_f32_16x16x32_bf16(a, bx, acc, 0, 0, 0);
            }
        }
        __syncthreads();                       // all waves done reading ws
        if (ct < 4) stage_w(ct + 1);           // transpose next tile
        if (ct == 0) {                         // store f/g
#pragma unroll
            for (int r = 0; r < 4; ++r) {
                int grow = rb * 32 + rg0 * 16 + q * 4 + r;
                int col = cg0 * 16 + n15;
                unsigned short v = f2bf(acc[r]);
                if (col < 32) f[grow * 32 + col] = v;
                else          g[grow * 32 + (col - 32)] = v;
            }
        } else {                               // store hT2
#pragma unroll
            for (int r = 0; r < 4; ++r) {
                int ch = (ct - 1) * 64 + cgh * 16 + q * 4 + r;
                int key = nbase + rgh * 16 + n15;
                hT[((b * 512 + (key >> 3)) * 256 + ch) * 8 + (key & 7)] = f2bf(acc[r]);
            }
        }
        __syncthreads();                       // tile ct+1 complete
    }
}

// ---------------- Kernel 2: fused flash attention + residual -------------
// EXACT R8 body (verified 56.7 us): direct-L2 coalesced H via hT2 layout,
// no hs staging, key-split S waves, exp2 path, cvt_pk packing, setprio,
// Q-tile 64 rows, grid 512 = 2 WGs/CU. R9 (2-tile phases), R12 (4 WG/CU)
// both regressed -> this structure is the attn local optimum.
__global__ __launch_bounds__(512, 4) void k_attn(const float* __restrict__ x,
                                                 const unsigned short* __restrict__ f,
                                                 const unsigned short* __restrict__ g,
                                                 const unsigned short* __restrict__ hT,
                                                 const float* __restrict__ gamma_p,
                                                 float* __restrict__ out) {
    __shared__ unsigned short pls[2][4096];    // P dbuf: 64 rows x 64 keys 16 KB
    __shared__ float lpart[4][64];             // per-S-wave key-partial row sums
    __shared__ __align__(16) float lrec[64];   // per-row 1/l
    int t = threadIdx.x, bx = blockIdx.x;
    int b = (bx >> 1) & 3;                     // one batch per XCD-pair
    int ch2 = (bx >> 3) & 1;                   // channel half (128 ch)
    int qt = ((bx & 1) << 5) | (bx >> 4);      // 64 Q-tiles of 64 rows
    int qbase = qt * 64;
    int chbase = ch2 * 128;
    int w = t >> 6, l = t & 63;
    int hi = l >> 5, l31 = l & 31;             // 32x32 roles (PV)
    int q = l >> 4, n15 = l & 15;              // 16x16 roles (S)
    int cb = w & 3;                            // PV ch-block (w>=4)
    const bool is_s = (w < 4);

    // ---- S-wave state: key-split. Wave w owns keys [kt*64+w*16, +16). ----
    bf16x8 aFB[4];
    const unsigned short* gW = g + (b * 4096 + w * 16 + n15) * 32 + q * 8;  // +kt*2048
    if (is_s) {
#pragma unroll
        for (int nt = 0; nt < 4; ++nt)
            aFB[nt] = *(const bf16x8*)&f[(b * 4096 + qbase + nt * 16 + n15) * 32 + q * 8];
    }
    bf16x8 aG, aGn;
    f32x4 lac = (f32x4){0.f, 0.f, 0.f, 0.f};   // l partials per nt (row group)
    const f32x4 zero4 = (f32x4){0.f, 0.f, 0.f, 0.f};

    // ---- PV-wave state: coalesced hT2 pointer + reg dbuf ----
    // hT2 idx = ((b*512 + kb)*256 + ch)*8 + k8 ; kb = kt*8 + 2ks + hi.
    const unsigned short* hb2 = hT + b * 1048576
                              + (chbase + cb * 32 + l31) * 8 + hi * 2048;
    bf16x8 bHc[4], bHn[4];

    // S-step for tile in aG -> pls[buf].
    // D[m=key w*16+4q+r][n=qrow nt*16+n15]; key-quad kq = 4w+q.
    auto s_tile = [&](int buf) {
        f32x4 sa[4];
#pragma unroll
        for (int nt = 0; nt < 4; ++nt)
            sa[nt] = __builtin_amdgcn_mfma_f32_16x16x32_bf16(aG, aFB[nt], zero4, 0, 0, 0);
        int kq = w * 4 + q;
#pragma unroll
        for (int nt = 0; nt < 4; ++nt) {
#pragma unroll
            for (int r = 0; r < 4; ++r) {
                sa[nt][r] = fexp2(sa[nt][r]);  // f pre-scaled by log2(e)
                lac[nt] += sa[nt][r];
            }
            unsigned p0 = cvt_pk_bf16(sa[nt][0], sa[nt][1]);
            unsigned p1 = cvt_pk_bf16(sa[nt][2], sa[nt][3]);
            int row = nt * 16 + n15;
            // phys = row*128B + ((kq>>1)^(row&7))*16B + (kq&1)*8B
            unsigned* dst = (unsigned*)&pls[buf][row * 64]
                          + (((kq >> 1) ^ (n15 & 7)) << 2) + ((kq & 1) << 1);
            dst[0] = p0; dst[1] = p1;
        }
    };

    f32x16 o0, o1;
#pragma unroll
    for (int i = 0; i < 16; ++i) { o0[i] = 0.f; o1[i] = 0.f; }

    // ---- prologue: S(0) -> pls[0]; PV loads bH(0); aG <- tile 1 ----
    if (is_s) {
        aG  = *(const bf16x8*)&gW[0];
        aGn = *(const bf16x8*)&gW[2048];
        s_tile(0);
        aG = aGn;
        __builtin_amdgcn_sched_barrier(0);
        asm volatile("s_waitcnt lgkmcnt(0)" ::: "memory");
    } else {
#pragma unroll
        for (int ks = 0; ks < 4; ++ks)
            bHc[ks] = *(const bf16x8*)&hb2[ks * 4096];
        __builtin_amdgcn_sched_barrier(0);
    }
    __builtin_amdgcn_s_barrier();              // publishes pls[0]
    __builtin_amdgcn_sched_barrier(0);

#pragma unroll 2
    for (int kt = 0; kt < 64; ++kt) {
        int cur = kt & 1, nxt = cur ^ 1;

        if (is_s) {
            if (kt + 1 < 64) {
                int ktn = (kt + 2 < 64) ? kt + 2 : 63;
                aGn = *(const bf16x8*)&gW[ktn * 2048];   // flies during s_tile
                s_tile(nxt);                             // S(kt+1) from aG
                aG = aGn;
            }
            __builtin_amdgcn_sched_barrier(0);
            asm volatile("s_waitcnt lgkmcnt(0)" ::: "memory");  // pls[nxt] visible
        } else {
            if (kt + 1 < 64) {                 // issue bH(kt+1) early (T14)
#pragma unroll
                for (int ks = 0; ks < 4; ++ks)
                    bHn[ks] = *(const bf16x8*)&hb2[(kt + 1) * 16384 + ks * 4096];
            }
            // ---- O += P(kt).H(kt) : 32x32x16, 4 key-steps ----
            const unsigned short* pcur = &pls[cur][0];
            __builtin_amdgcn_s_setprio(1);
#pragma unroll
            for (int ks = 0; ks < 4; ++ks) {
                int seg = (((2 * ks + hi) ^ (l31 & 7)) << 3);
                bf16x8 aP0 = *(const bf16x8*)&pcur[l31 * 64 + seg];
                bf16x8 aP1 = *(const bf16x8*)&pcur[(32 + l31) * 64 + seg];
                o0 = __builtin_amdgcn_mfma_f32_32x32x16_bf16(aP0, bHc[ks], o0, 0, 0, 0);
                o1 = __builtin_amdgcn_mfma_f32_32x32x16_bf16(aP1, bHc[ks], o1, 0, 0, 0);
            }
            __builtin_amdgcn_s_setprio(0);
            if (kt + 1 < 64) {
#pragma unroll
                for (int ks = 0; ks < 4; ++ks) bHc[ks] = bHn[ks];
            }
            __builtin_amdgcn_sched_barrier(0);
        }

        __builtin_amdgcn_s_barrier();          // publish pls[nxt]
        __builtin_amdgcn_sched_barrier(0);
    }

    // ---- epilogue: l reduce (4 key-partials per row), O/l, residual ----
    if (is_s) {
#pragma unroll
        for (int nt = 0; nt < 4; ++nt) {
            float ps = lac[nt];
            ps += __shfl_xor(ps, 16);
            ps += __shfl_xor(ps, 32);
            if (q == 0) lpart[w][nt * 16 + n15] = ps;
        }
    }
    __syncthreads();
    if (t < 64) lrec[t] = 1.0f / (lpart[0][t] + lpart[1][t] + lpart[2][t] + lpart[3][t]);
    __syncthreads();
    if (!is_s) {
        float gam = *gamma_p;
        int ch = chbase + cb * 32 + l31;
#pragma unroll
        for (int qq = 0; qq < 4; ++qq) {
            int r0 = 8 * qq + 4 * hi;
            f32x4 ri0 = *(const f32x4*)&lrec[r0];
            f32x4 ri1 = *(const f32x4*)&lrec[32 + r0];
#pragma unroll
            for (int j = 0; j < 4; ++j) {
                int idx0 = (b * 4096 + qbase + r0 + j) * 256 + ch;
                int idx1 = idx0 + 32 * 256;
                out[idx0] = x[idx0] + gam * (o0[4 * qq + j] * ri0[j]);
                out[idx1] = x[idx1] + gam * (o1[4 * qq + j] * ri1[j]);
            }
        }
    }
}

// ---------------- launch ------------------------------------------------
extern "C" void kernel_launch(void* const* d_in, const int* in_sizes, int n_in,
                              void* d_out, int out_size, void* d_ws, size_t ws_size,
                              hipStream_t stream) {
    const float* x  = (const float*)d_in[0];
    const float* kf = (const float*)d_in[1];
    const float* kg = (const float*)d_in[2];
    const float* kh = (const float*)d_in[3];
    const float* gm = (const float*)d_in[4];
    float* out = (float*)d_out;

    char* ws = (char*)d_ws;
    unsigned short* fb = (unsigned short*)(ws + 163840);    // 16384*32*2  = 1 MiB
    unsigned short* gb = (unsigned short*)(ws + 1212416);   // 16384*32*2  = 1 MiB
    unsigned short* hT = (unsigned short*)(ws + 2260992);   // 4*512*256*8*2 = 8 MiB

    hipLaunchKernelGGL(k_proj, dim3(512), dim3(512), 0, stream, x, kf, kg, kh, fb, gb, hT);
    hipLaunchKernelGGL(k_attn, dim3(512), dim3(512), 0, stream, x, fb, gb, hT, gm, out);
}

// Round 14
// 136.092 us; speedup vs baseline: 2.9127x; 1.0993x over previous
//
#include <hip/hip_runtime.h>

typedef __attribute__((ext_vector_type(8))) short bf16x8;
typedef __attribute__((ext_vector_type(4))) float f32x4;
typedef __attribute__((ext_vector_type(16))) float f32x16;

__device__ __forceinline__ unsigned short f2bf(float f) {  // RNE
    union { float f; unsigned u; } v; v.f = f;
    return (unsigned short)((v.u + 0x7FFFu + ((v.u >> 16) & 1u)) >> 16);
}

__device__ __forceinline__ float fexp2(float v) {
#if __has_builtin(__builtin_amdgcn_exp2f)
    return __builtin_amdgcn_exp2f(v);
#else
    float r; asm("v_exp_f32 %0, %1" : "=v"(r) : "v"(v)); return r;
#endif
}
// pack two f32 -> two bf16 (RNE) in one instr (T12 primitive)
__device__ __forceinline__ unsigned cvt_pk_bf16(float lo, float hi) {
    unsigned r;
    asm("v_cvt_pk_bf16_f32 %0, %1, %2" : "=v"(r) : "v"(lo), "v"(hi));
    return r;
}

__device__ __forceinline__ void async16(unsigned short* lds, const unsigned short* gsrc) {
    __builtin_amdgcn_global_load_lds(
        (const __attribute__((address_space(1))) void*)gsrc,
        (__attribute__((address_space(3))) void*)lds, 16, 0, 0);
}

// ---------------- Kernel 0: weight transpose + bf16 cast (swizzled) ------
// kf rows (n<32) pre-scaled by log2(e): softmax exp(s) == exp2(s_scaled).
// R13 showed fusing this into k_proj costs MORE than the dispatch saves
// (scalar swizzled LDS writes vs 16-B DMA): keep the separate kernel.
__global__ __launch_bounds__(256) void k_wt(const float* __restrict__ kf,
                                            const float* __restrict__ kg,
                                            const float* __restrict__ kh,
                                            unsigned short* __restrict__ wt) {
    int n = blockIdx.x, t = threadIdx.x;
    const float* src; int stride, col;
    if (n < 32)      { src = kf; stride = 32;  col = n; }
    else if (n < 64) { src = kg; stride = 32;  col = n - 32; }
    else             { src = kh; stride = 256; col = n - 64; }
    float v = src[t * stride + col];
    if (n < 32) v *= 1.44269504088896341f;     // log2(e)
    wt[n * 256 + (((t >> 3) ^ (n & 7)) << 3) + (t & 7)] = f2bf(v);
}

// ---------------- Kernel 1: projections (R8 verified) --------------------
// hT2[b][kb][ch][k8]: kb = key>>3, k8 = key&7 -> k_attn PV fragments are
// coalesced 16B-per-lane global loads.
__global__ __launch_bounds__(512) void k_proj(const float* __restrict__ x,
                                              const unsigned short* __restrict__ wt,
                                              unsigned short* __restrict__ f,
                                              unsigned short* __restrict__ g,
                                              unsigned short* __restrict__ hT) {
    __shared__ unsigned short xs[8192];       // 32 x 256 bf16, swizzled  16 KB
    __shared__ unsigned short ws[16384];      // one 64-col W tile        32 KB
    int t = threadIdx.x, rb = blockIdx.x;     // 512 row-blocks of 32 rows
    int w = t >> 6, lane = t & 63, q = lane >> 4, n15 = lane & 15;
    int b = rb >> 7, nbase = (rb & 127) * 32;
    int rg0 = w & 1, cg0 = w >> 1;            // ct0: 2 rowg x 4 colg
    int cgh = w & 3, rgh = w >> 2;            // ct>=1: 4 chg x 2 rowg

#pragma unroll
    for (int i = 0; i < 4; ++i) {
        int lin = i * 512 + t, row = lin >> 6, c4 = lin & 63;
        float4 v = *(const float4*)&x[(rb * 32 + row) * 256 + c4 * 4];
        ushort4 o; o.x = f2bf(v.x); o.y = f2bf(v.y); o.z = f2bf(v.z); o.w = f2bf(v.w);
        *(ushort4*)&xs[row * 256 + (((c4 >> 1) ^ (row & 7)) << 3) + ((c4 & 1) << 2)] = o;
    }
#pragma unroll
    for (int j = 0; j < 4; ++j)
        async16(&ws[(j * 512 + w * 64) * 8], wt + (j * 512 + t) * 8);
    __syncthreads();                           // xs + tile0 ready

    for (int ct = 0; ct < 5; ++ct) {
        f32x4 acc = (f32x4){0.f, 0.f, 0.f, 0.f};
        if (ct == 0) {                         // f,g : D[m=row][n=col]
#pragma unroll
            for (int kk = 0; kk < 8; ++kk) {
                bf16x8 a = *(const bf16x8*)&xs[(rg0 * 16 + n15) * 256
                                + ((((kk << 2) + q) ^ (n15 & 7)) << 3)];
                bf16x8 bw = *(const bf16x8*)&ws[(cg0 * 16 + n15) * 256
                                + ((((kk << 2) + q) ^ (n15 & 7)) << 3)];
                acc = __builtin_amdgcn_mfma_f32_16x16x32_bf16(a, bw, acc, 0, 0, 0);
            }
        } else {                               // h : D[m=ch][n=row] (swapped)
#pragma unroll
            for (int kk = 0; kk < 8; ++kk) {
                bf16x8 a = *(const bf16x8*)&ws[(cgh * 16 + n15) * 256
                                + ((((kk << 2) + q) ^ (n15 & 7)) << 3)];
                bf16x8 bx = *(const bf16x8*)&xs[(rgh * 16 + n15) * 256
                                + ((((kk << 2) + q) ^ (n15 & 7)) << 3)];
                acc = __builtin_amdgcn_mfma_f32_16x16x32_bf16(a, bx, acc, 0, 0, 0);
            }
        }
        __syncthreads();                       // all waves done reading ws
        if (ct < 4) {                          // DMA tile ct+1 (flies over stores)
            const unsigned short* wsrc = wt + (ct + 1) * 16384;
#pragma unroll
            for (int j = 0; j < 4; ++j)
                async16(&ws[(j * 512 + w * 64) * 8], wsrc + (j * 512 + t) * 8);
        }
        if (ct == 0) {                         // store f/g (overlaps DMA)
#pragma unroll
            for (int r = 0; r < 4; ++r) {
                int grow = rb * 32 + rg0 * 16 + q * 4 + r;
                int col = cg0 * 16 + n15;
                unsigned short v = f2bf(acc[r]);
                if (col < 32) f[grow * 32 + col] = v;
                else          g[grow * 32 + (col - 32)] = v;
            }
        } else {                               // store hT2 (overlaps DMA)
#pragma unroll
            for (int r = 0; r < 4; ++r) {
                int ch = (ct - 1) * 64 + cgh * 16 + q * 4 + r;
                int key = nbase + rgh * 16 + n15;
                hT[((b * 512 + (key >> 3)) * 256 + ch) * 8 + (key & 7)] = f2bf(acc[r]);
            }
        }
        __syncthreads();                       // tile ct+1 landed
    }
}

// ---------------- Kernel 2: fused flash attention + residual -------------
// EXACT R8 body (session-best, verified 56.7 us / total 137.0):
//   direct-L2 coalesced H via hT2 layout (no hs staging), key-split S
//   waves, exp2 path, cvt_pk packing, setprio, Q-tile 64 rows,
//   grid 512 = 2 WGs/CU. Structural alternatives all regressed:
//   R9 2-tile phases (+0%, +scratch), R12 4 WG/CU (+30% time),
//   R4 frag hoist (+13%), R13 wt-fusion (+12 total). pls 4-way read
//   conflict is irreducible at 128B row stride with 16B-aligned b128.
__global__ __launch_bounds__(512, 4) void k_attn(const float* __restrict__ x,
                                                 const unsigned short* __restrict__ f,
                                                 const unsigned short* __restrict__ g,
                                                 const unsigned short* __restrict__ hT,
                                                 const float* __restrict__ gamma_p,
                                                 float* __restrict__ out) {
    __shared__ unsigned short pls[2][4096];    // P dbuf: 64 rows x 64 keys 16 KB
    __shared__ float lpart[4][64];             // per-S-wave key-partial row sums
    __shared__ __align__(16) float lrec[64];   // per-row 1/l
    int t = threadIdx.x, bx = blockIdx.x;
    int b = (bx >> 1) & 3;                     // one batch per XCD-pair
    int ch2 = (bx >> 3) & 1;                   // channel half (128 ch)
    int qt = ((bx & 1) << 5) | (bx >> 4);      // 64 Q-tiles of 64 rows
    int qbase = qt * 64;
    int chbase = ch2 * 128;
    int w = t >> 6, l = t & 63;
    int hi = l >> 5, l31 = l & 31;             // 32x32 roles (PV)
    int q = l >> 4, n15 = l & 15;              // 16x16 roles (S)
    int cb = w & 3;                            // PV ch-block (w>=4)
    const bool is_s = (w < 4);

    // ---- S-wave state: key-split. Wave w owns keys [kt*64+w*16, +16). ----
    bf16x8 aFB[4];
    const unsigned short* gW = g + (b * 4096 + w * 16 + n15) * 32 + q * 8;  // +kt*2048
    if (is_s) {
#pragma unroll
        for (int nt = 0; nt < 4; ++nt)
            aFB[nt] = *(const bf16x8*)&f[(b * 4096 + qbase + nt * 16 + n15) * 32 + q * 8];
    }
    bf16x8 aG, aGn;
    f32x4 lac = (f32x4){0.f, 0.f, 0.f, 0.f};   // l partials per nt (row group)
    const f32x4 zero4 = (f32x4){0.f, 0.f, 0.f, 0.f};

    // ---- PV-wave state: coalesced hT2 pointer + reg dbuf ----
    // hT2 idx = ((b*512 + kb)*256 + ch)*8 + k8 ; kb = kt*8 + 2ks + hi.
    const unsigned short* hb2 = hT + b * 1048576
                              + (chbase + cb * 32 + l31) * 8 + hi * 2048;
    bf16x8 bHc[4], bHn[4];

    // S-step for tile in aG -> pls[buf].
    // D[m=key w*16+4q+r][n=qrow nt*16+n15]; key-quad kq = 4w+q.
    auto s_tile = [&](int buf) {
        f32x4 sa[4];
#pragma unroll
        for (int nt = 0; nt < 4; ++nt)
            sa[nt] = __builtin_amdgcn_mfma_f32_16x16x32_bf16(aG, aFB[nt], zero4, 0, 0, 0);
        int kq = w * 4 + q;
#pragma unroll
        for (int nt = 0; nt < 4; ++nt) {
#pragma unroll
            for (int r = 0; r < 4; ++r) {
                sa[nt][r] = fexp2(sa[nt][r]);  // f pre-scaled by log2(e)
                lac[nt] += sa[nt][r];
            }
            unsigned p0 = cvt_pk_bf16(sa[nt][0], sa[nt][1]);
            unsigned p1 = cvt_pk_bf16(sa[nt][2], sa[nt][3]);
            int row = nt * 16 + n15;
            // phys = row*128B + ((kq>>1)^(row&7))*16B + (kq&1)*8B
            unsigned* dst = (unsigned*)&pls[buf][row * 64]
                          + (((kq >> 1) ^ (n15 & 7)) << 2) + ((kq & 1) << 1);
            dst[0] = p0; dst[1] = p1;
        }
    };

    f32x16 o0, o1;
#pragma unroll
    for (int i = 0; i < 16; ++i) { o0[i] = 0.f; o1[i] = 0.f; }

    // ---- prologue: S(0) -> pls[0]; PV loads bH(0); aG <- tile 1 ----
    if (is_s) {
        aG  = *(const bf16x8*)&gW[0];
        aGn = *(const bf16x8*)&gW[2048];
        s_tile(0);
        aG = aGn;
        __builtin_amdgcn_sched_barrier(0);
        asm volatile("s_waitcnt lgkmcnt(0)" ::: "memory");
    } else {
#pragma unroll
        for (int ks = 0; ks < 4; ++ks)
            bHc[ks] = *(const bf16x8*)&hb2[ks * 4096];
        __builtin_amdgcn_sched_barrier(0);
    }
    __builtin_amdgcn_s_barrier();              // publishes pls[0]
    __builtin_amdgcn_sched_barrier(0);

#pragma unroll 2
    for (int kt = 0; kt < 64; ++kt) {
        int cur = kt & 1, nxt = cur ^ 1;

        if (is_s) {
            if (kt + 1 < 64) {
                int ktn = (kt + 2 < 64) ? kt + 2 : 63;
                aGn = *(const bf16x8*)&gW[ktn * 2048];   // flies during s_tile
                s_tile(nxt);                             // S(kt+1) from aG
                aG = aGn;
            }
            __builtin_amdgcn_sched_barrier(0);
            asm volatile("s_waitcnt lgkmcnt(0)" ::: "memory");  // pls[nxt] visible
        } else {
            if (kt + 1 < 64) {                 // issue bH(kt+1) early (T14)
#pragma unroll
                for (int ks = 0; ks < 4; ++ks)
                    bHn[ks] = *(const bf16x8*)&hb2[(kt + 1) * 16384 + ks * 4096];
            }
            // ---- O += P(kt).H(kt) : 32x32x16, 4 key-steps ----
            const unsigned short* pcur = &pls[cur][0];
            __builtin_amdgcn_s_setprio(1);
#pragma unroll
            for (int ks = 0; ks < 4; ++ks) {
                int seg = (((2 * ks + hi) ^ (l31 & 7)) << 3);
                bf16x8 aP0 = *(const bf16x8*)&pcur[l31 * 64 + seg];
                bf16x8 aP1 = *(const bf16x8*)&pcur[(32 + l31) * 64 + seg];
                o0 = __builtin_amdgcn_mfma_f32_32x32x16_bf16(aP0, bHc[ks], o0, 0, 0, 0);
                o1 = __builtin_amdgcn_mfma_f32_32x32x16_bf16(aP1, bHc[ks], o1, 0, 0, 0);
            }
            __builtin_amdgcn_s_setprio(0);
            if (kt + 1 < 64) {
#pragma unroll
                for (int ks = 0; ks < 4; ++ks) bHc[ks] = bHn[ks];
            }
            __builtin_amdgcn_sched_barrier(0);
        }

        __builtin_amdgcn_s_barrier();          // publish pls[nxt]
        __builtin_amdgcn_sched_barrier(0);
    }

    // ---- epilogue: l reduce (4 key-partials per row), O/l, residual ----
    if (is_s) {
#pragma unroll
        for (int nt = 0; nt < 4; ++nt) {
            float ps = lac[nt];
            ps += __shfl_xor(ps, 16);
            ps += __shfl_xor(ps, 32);
            if (q == 0) lpart[w][nt * 16 + n15] = ps;
        }
    }
    __syncthreads();
    if (t < 64) lrec[t] = 1.0f / (lpart[0][t] + lpart[1][t] + lpart[2][t] + lpart[3][t]);
    __syncthreads();
    if (!is_s) {
        float gam = *gamma_p;
        int ch = chbase + cb * 32 + l31;
#pragma unroll
        for (int qq = 0; qq < 4; ++qq) {
            int r0 = 8 * qq + 4 * hi;
            f32x4 ri0 = *(const f32x4*)&lrec[r0];
            f32x4 ri1 = *(const f32x4*)&lrec[32 + r0];
#pragma unroll
            for (int j = 0; j < 4; ++j) {
                int idx0 = (b * 4096 + qbase + r0 + j) * 256 + ch;
                int idx1 = idx0 + 32 * 256;
                out[idx0] = x[idx0] + gam * (o0[4 * qq + j] * ri0[j]);
                out[idx1] = x[idx1] + gam * (o1[4 * qq + j] * ri1[j]);
            }
        }
    }
}

// ---------------- launch ------------------------------------------------
extern "C" void kernel_launch(void* const* d_in, const int* in_sizes, int n_in,
                              void* d_out, int out_size, void* d_ws, size_t ws_size,
                              hipStream_t stream) {
    const float* x  = (const float*)d_in[0];
    const float* kf = (const float*)d_in[1];
    const float* kg = (const float*)d_in[2];
    const float* kh = (const float*)d_in[3];
    const float* gm = (const float*)d_in[4];
    float* out = (float*)d_out;

    char* ws = (char*)d_ws;
    unsigned short* wt = (unsigned short*)(ws);             // 320*256*2   = 163840 B
    unsigned short* fb = (unsigned short*)(ws + 163840);    // 16384*32*2  = 1 MiB
    unsigned short* gb = (unsigned short*)(ws + 1212416);   // 16384*32*2  = 1 MiB
    unsigned short* hT = (unsigned short*)(ws + 2260992);   // 4*512*256*8*2 = 8 MiB

    hipLaunchKernelGGL(k_wt,   dim3(320), dim3(256), 0, stream, kf, kg, kh, wt);
    hipLaunchKernelGGL(k_proj, dim3(512), dim3(512), 0, stream, x, wt, fb, gb, hT);
    hipLaunchKernelGGL(k_attn, dim3(512), dim3(512), 0, stream, x, fb, gb, hT, gm, out);
}